// Round 21
// baseline (52.748 us; speedup 1.0000x reference)
//
#include <hip/hip_runtime.h>
#include <stdint.h>

#define K_DIM 4096
#define N_DIM 11008
#define M_DIM 256

typedef uint32_t u32;
using frag_ab = __attribute__((ext_vector_type(8))) short;   // 8 bf16
using frag_cd = __attribute__((ext_vector_type(4))) float;   // 4 f32

typedef __attribute__((address_space(3))) const char lds_cc;

#define DSR128(dst, addr, off)                                       \
    asm volatile("ds_read_b128 %0, %1 offset:" #off                  \
                 : "=&v"(dst) : "v"(addr))
#define DSR32(dst, addr, off)                                        \
    asm volatile("ds_read_b32 %0, %1 offset:" #off                   \
                 : "=&v"(dst) : "v"(addr))
#define LGKM(n) do { asm volatile("s_waitcnt lgkmcnt(" #n ")" ::: "memory"); \
                     __builtin_amdgcn_sched_barrier(0); } while (0)
#define VMW(n) asm volatile("s_waitcnt vmcnt(" #n ")" ::: "memory")

__device__ __forceinline__ u32 f2bf_rn(float f) {
    u32 u = __builtin_bit_cast(u32, f);
    return (u + 0x7FFFu + ((u >> 16) & 1u)) >> 16;   // round-to-nearest-even
}
__device__ __forceinline__ float bf2f(u32 b) {
    return __builtin_bit_cast(float, b << 16);
}
__device__ __forceinline__ void gll16(const void* g, void* l) {
    __builtin_amdgcn_global_load_lds(
        (const __attribute__((address_space(1))) u32*)g,
        (__attribute__((address_space(3))) u32*)l, 16, 0, 0);
}

// bf16(32+v) = 0x4200 | (v<<2); q*0x4004 = q<<14|q<<2 -> packed bf16x2.
#define BFCVT(q) ((u32)((__mul24((int)(q), 0x4004) & 0x003C003C) | 0x42004200))

// Kernel 1: x f32 -> bf16 (RN) + per-row sums of the ROUNDED values.
__global__ __launch_bounds__(256) void prep_kernel(const float* __restrict__ x,
                                                   ushort* __restrict__ xbf,
                                                   float* __restrict__ rowsum) {
    const int row = blockIdx.x;
    const int tid = threadIdx.x;
    const float* xr = x + (size_t)row * K_DIM;
    ushort* br = xbf + (size_t)row * K_DIM;
    float s = 0.0f;
#pragma unroll
    for (int p = 0; p < 4; ++p) {
        int i = p * 1024 + tid * 4;
        float4 v = *reinterpret_cast<const float4*>(xr + i);
        u32 b0 = f2bf_rn(v.x), b1 = f2bf_rn(v.y), b2 = f2bf_rn(v.z), b3 = f2bf_rn(v.w);
        uint2 o;
        o.x = b0 | (b1 << 16);
        o.y = b2 | (b3 << 16);
        *reinterpret_cast<uint2*>(br + i) = o;
        s += bf2f(b0) + bf2f(b1) + bf2f(b2) + bf2f(b3);
    }
#pragma unroll
    for (int off = 32; off > 0; off >>= 1) s += __shfl_down(s, off, 64);
    __shared__ float wsum[4];
    if ((tid & 63) == 0) wsum[tid >> 6] = s;
    __syncthreads();
    if (tid == 0) rowsum[row] = wsum[0] + wsum[1] + wsum[2] + wsum[3];
}

// Kernel 2: BM=128, BN=128, BK=64, split-K=4 -> 16 tiles/block, grid 688.
// 4 waves (2m x 2n), wave tile 64x64x64k = 32 MFMA per tile-event (2x r20:
// halves the measured per-tile sync cost budget).  64 KB double-buffered
// LDS -> 2 blocks/CU.  r15-verified A staging/swizzle; r20-verified B
// staging/swizzle + grouped-lgkm consume, run per 32-k step.
__global__ __launch_bounds__(256, 2) void gemm_kernel(const int* __restrict__ qw,
                                                      const float* __restrict__ scales,
                                                      const float* __restrict__ zeroes,
                                                      const ushort* __restrict__ xbf,
                                                      const float* __restrict__ rowsum,
                                                      float* __restrict__ out,
                                                      ushort* __restrict__ partial,
                                                      int split4) {
    // A tile: [m 0..127][chunk 0..7 of 16B], stored chunk' = chunk ^ (m&7)
    // B tile: [row 0..31][col 0..127] dwords, stored col' = col ^ (((row>>2)&1)<<4)
    __shared__ uint4 Alds[2][1024];   // 2 x 16 KB
    __shared__ u32   Blds[2][4096];   // 2 x 16 KB

    const u32* qwu = (const u32*)qw;
    const int tid  = threadIdx.x;
    const int lane = tid & 63;
    const int wid  = tid >> 6;
    const int l4   = lane & 15;
    const int c    = lane >> 4;

    // XCD-bijective swizzle (688 = 8*86): the 8 blocks (2mb x 4sp) of one
    // n-strip are consecutive wg -> same XCD L2 for the shared B slice.
    const int orig = blockIdx.x;
    int nb, mb, sp, NTt;
    if (split4) {
        int wg = (orig & 7) * 86 + (orig >> 3);
        nb = wg >> 3; sp = (wg >> 1) & 3; mb = wg & 1; NTt = 16;
    } else {
        nb = orig >> 1; mb = orig & 1; sp = 0; NTt = 64;
    }
    const int n0 = nb * 128;
    const int m0 = mb * 128;
    const int wm = wid >> 1;
    const int wn = wid & 1;

    // ---- staging sources (pre-swizzled: linear LDS dest = swizzled layout)
    // A round j (r15-verified): row m0 + j*32 + wid*8 + (lane>>3),
    //                           chunk (lane&7) ^ (lane>>3)
    const ushort* asrc[4];
#pragma unroll
    for (int j = 0; j < 4; ++j)
        asrc[j] = xbf + (size_t)(m0 + j * 32 + wid * 8 + (lane >> 3)) * K_DIM +
                  sp * 1024 + ((lane & 7) ^ (lane >> 3)) * 8;
    // B round r (r20-verified pattern, extended to 32 rows): packed row
    // r*8 + wid*2 + (lane>>5), col chunk (lane&31) ^ (((wid>>1)&1)<<2)
    const u32* bsrc[4];
#pragma unroll
    for (int r = 0; r < 4; ++r)
        bsrc[r] = qwu + (size_t)(sp * 512 + r * 8 + wid * 2 + (lane >> 5)) * N_DIM +
                  n0 + 4 * ((lane & 31) ^ (((wid >> 1) & 1) << 2));

    // ---- LDS read byte-offsets
    const u32 aoff0 = (u32)((wm * 64 + l4) * 128 + (((0 + c) ^ (l4 & 7)) << 4));
    const u32 aoff1 = (u32)((wm * 64 + l4) * 128 + (((4 + c) ^ (l4 & 7)) << 4));
    const u32 b0off = (u32)((c * 4) * 512 + (wn * 64 + ((c & 1) << 4) + l4) * 4);
    const u32 b1off = (u32)((c * 4) * 512 + (wn * 64 + (((c & 1) ^ 1) << 4) + l4) * 4);

    frag_cd acc[4][4];
#pragma unroll
    for (int i = 0; i < 4; ++i)
#pragma unroll
        for (int j = 0; j < 4; ++j)
            acc[i][j] = (frag_cd){0.f, 0.f, 0.f, 0.f};

    auto stage = [&](int t, int buf) {      // 8 x global_load_lds(16B)
#pragma unroll
        for (int j = 0; j < 4; ++j)
            gll16(asrc[j] + (size_t)t * 64, &Alds[buf][j * 256 + wid * 64]);
#pragma unroll
        for (int r = 0; r < 4; ++r)
            gll16(bsrc[r] + (size_t)t * 32 * N_DIM, &Blds[buf][r * 1024 + wid * 256]);
    };

    // One 32-k step: 4 A-b128 + 16 B-b32 (nf-major), grouped-lgkm consume.
#define KSTEP(AOFF, I0, I1, I2, I3, I4, I5, I6, I7, I8, I9, Ia, Ib, Ic, Id, Ie, If) { \
        frag_ab afr[4];                                                      \
        DSR128(afr[0], Ab + AOFF, 0);                                        \
        DSR128(afr[1], Ab + AOFF, 2048);                                     \
        DSR128(afr[2], Ab + AOFF, 4096);                                     \
        DSR128(afr[3], Ab + AOFF, 6144);                                     \
        u32 bq[16];                                                          \
        DSR32(bq[0],  Bb + b0off, I0);  DSR32(bq[1],  Bb + b0off, I1);       \
        DSR32(bq[2],  Bb + b0off, I2);  DSR32(bq[3],  Bb + b0off, I3);       \
        DSR32(bq[4],  Bb + b1off, I4);  DSR32(bq[5],  Bb + b1off, I5);       \
        DSR32(bq[6],  Bb + b1off, I6);  DSR32(bq[7],  Bb + b1off, I7);       \
        DSR32(bq[8],  Bb + b0off, I8);  DSR32(bq[9],  Bb + b0off, I9);       \
        DSR32(bq[10], Bb + b0off, Ia);  DSR32(bq[11], Bb + b0off, Ib);       \
        DSR32(bq[12], Bb + b1off, Ic);  DSR32(bq[13], Bb + b1off, Id);       \
        DSR32(bq[14], Bb + b1off, Ie);  DSR32(bq[15], Bb + b1off, If);       \
        LGKM(12);                                                            \
        _Pragma("unroll")                                                    \
        for (int nf = 0; nf < 4; ++nf) {                                     \
            union { frag_ab f; u32 u[4]; } bb;                               \
            bb.u[0] = BFCVT(bq[nf * 4 + 0]);                                 \
            bb.u[1] = BFCVT(bq[nf * 4 + 1]);                                 \
            bb.u[2] = BFCVT(bq[nf * 4 + 2]);                                 \
            bb.u[3] = BFCVT(bq[nf * 4 + 3]);                                 \
            _Pragma("unroll")                                                \
            for (int mf = 0; mf < 4; ++mf)                                   \
                acc[mf][nf] = __builtin_amdgcn_mfma_f32_16x16x32_bf16(       \
                    afr[mf], bb.f, acc[mf][nf], 0, 0, 0);                    \
            if (nf == 0)      LGKM(8);                                       \
            else if (nf == 1) LGKM(4);                                       \
            else if (nf == 2) LGKM(0);                                       \
        } }

    auto compute = [&](int buf) {
        lds_cc* Ab = (lds_cc*)&Alds[buf][0];
        lds_cc* Bb = (lds_cc*)&Blds[buf][0];
        KSTEP(aoff0, 0, 512, 1024, 1536, 0, 512, 1024, 1536,
              128, 640, 1152, 1664, 128, 640, 1152, 1664)
        KSTEP(aoff1, 8192, 8704, 9216, 9728, 8192, 8704, 9216, 9728,
              8320, 8832, 9344, 9856, 8320, 8832, 9344, 9856)
    };

    // prologue
    stage(0, 0);

    for (int t = 0; t < NTt; ++t) {
        int buf = t & 1;
        if (t + 1 < NTt) {
            stage(t + 1, buf ^ 1);
            VMW(8);                       // tile t's 8 loads landed
        } else {
            VMW(0);
        }
        __builtin_amdgcn_s_barrier();
        __builtin_amdgcn_sched_barrier(0);
        compute(buf);
        asm volatile("" ::: "memory");
        __builtin_amdgcn_s_barrier();     // all waves done before buf re-stage
    }

    // epilogue: rows m0 + wm*64 + mf*16 + c*4 + j; cols n0 + wn*64 + nf*16 + l4
    float sc[4], zp[4];
#pragma unroll
    for (int nf = 0; nf < 4; ++nf) {
        int n = n0 + wn * 64 + nf * 16 + l4;
        sc[nf] = scales[n];
        zp[nf] = zeroes[n] + 32.0f * sc[nf];
    }
    if (sp == 0) {
        float rs[4][4];
#pragma unroll
        for (int mf = 0; mf < 4; ++mf)
#pragma unroll
            for (int j = 0; j < 4; ++j)
                rs[mf][j] = rowsum[m0 + wm * 64 + mf * 16 + c * 4 + j];
#pragma unroll
        for (int mf = 0; mf < 4; ++mf)
#pragma unroll
            for (int nf = 0; nf < 4; ++nf)
#pragma unroll
                for (int j = 0; j < 4; ++j) {
                    int m = m0 + wm * 64 + mf * 16 + c * 4 + j;
                    out[(size_t)m * N_DIM + n0 + wn * 64 + nf * 16 + l4] =
                        sc[nf] * acc[mf][nf][j] - zp[nf] * rs[mf][j];
                }
    } else {
        ushort* pb = partial + (size_t)(sp - 1) * M_DIM * N_DIM;
#pragma unroll
        for (int mf = 0; mf < 4; ++mf)
#pragma unroll
            for (int nf = 0; nf < 4; ++nf)
#pragma unroll
                for (int j = 0; j < 4; ++j) {
                    int m = m0 + wm * 64 + mf * 16 + c * 4 + j;
                    pb[(size_t)m * N_DIM + n0 + wn * 64 + nf * 16 + l4] =
                        (ushort)f2bf_rn(sc[nf] * acc[mf][nf][j]);
                }
    }
#undef KSTEP
}

// Kernel 3: out += bf16-partials p0+p1+p2.  Exact cover: 2752 blocks *
// 256 threads * 4 floats = 2,818,048 = 256*11008.
__global__ __launch_bounds__(256) void reduce_kernel(float* __restrict__ out,
                                                     const ushort* __restrict__ partial) {
    const size_t NTOT = (size_t)M_DIM * N_DIM;
    size_t i = ((size_t)blockIdx.x * 256 + threadIdx.x) * 4;
    float4 o = *reinterpret_cast<float4*>(out + i);
    ushort4 a = *reinterpret_cast<const ushort4*>(partial + i);
    ushort4 b = *reinterpret_cast<const ushort4*>(partial + NTOT + i);
    ushort4 d = *reinterpret_cast<const ushort4*>(partial + 2 * NTOT + i);
    o.x += bf2f(a.x) + bf2f(b.x) + bf2f(d.x);
    o.y += bf2f(a.y) + bf2f(b.y) + bf2f(d.y);
    o.z += bf2f(a.z) + bf2f(b.z) + bf2f(d.z);
    o.w += bf2f(a.w) + bf2f(b.w) + bf2f(d.w);
    *reinterpret_cast<float4*>(out + i) = o;
}

extern "C" void kernel_launch(void* const* d_in, const int* in_sizes, int n_in,
                              void* d_out, int out_size, void* d_ws, size_t ws_size,
                              hipStream_t stream) {
    const float* x      = (const float*)d_in[0];
    const int*   qw     = (const int*)d_in[1];
    const float* scales = (const float*)d_in[2];
    const float* zeroes = (const float*)d_in[3];
    float* out = (float*)d_out;

    const size_t XBF_BYTES = (size_t)M_DIM * K_DIM * 2;        // 2 MB
    const size_t RS_OFF    = XBF_BYTES;                         // 1 KB
    const size_t P_OFF     = XBF_BYTES + 4096;
    const size_t P_BYTES   = (size_t)3 * M_DIM * N_DIM * 2;     // 16.9 MB bf16

    ushort* xbf    = (ushort*)d_ws;
    float*  rowsum = (float*)((char*)d_ws + RS_OFF);
    ushort* part   = (ushort*)((char*)d_ws + P_OFF);

    const bool split4 = ws_size >= P_OFF + P_BYTES;

    prep_kernel<<<M_DIM, 256, 0, stream>>>(x, xbf, rowsum);
    if (split4) {
        gemm_kernel<<<688, 256, 0, stream>>>(qw, scales, zeroes, xbf, rowsum,
                                             out, part, 1);
        reduce_kernel<<<(M_DIM * N_DIM) / (256 * 4), 256, 0, stream>>>(out, part);
    } else {
        gemm_kernel<<<172, 256, 0, stream>>>(qw, scales, zeroes, xbf, rowsum,
                                             out, nullptr, 0);
    }
}

// Round 22
// 49.143 us; speedup vs baseline: 1.0733x; 1.0733x over previous
//
#include <hip/hip_runtime.h>
#include <stdint.h>

#define K_DIM 4096
#define N_DIM 11008
#define M_DIM 256

typedef uint32_t u32;
using frag_ab = __attribute__((ext_vector_type(8))) short;   // 8 bf16
using frag_cd = __attribute__((ext_vector_type(4))) float;   // 4 f32

typedef __attribute__((address_space(3))) const char lds_cc;

#define DSR128(dst, addr, off)                                       \
    asm volatile("ds_read_b128 %0, %1 offset:" #off                  \
                 : "=&v"(dst) : "v"(addr))
#define DSR32(dst, addr, off)                                        \
    asm volatile("ds_read_b32 %0, %1 offset:" #off                   \
                 : "=&v"(dst) : "v"(addr))
#define LGKM(n) do { asm volatile("s_waitcnt lgkmcnt(" #n ")" ::: "memory"); \
                     __builtin_amdgcn_sched_barrier(0); } while (0)
#define VMW(n) asm volatile("s_waitcnt vmcnt(" #n ")" ::: "memory")

__device__ __forceinline__ u32 f2bf_rn(float f) {
    u32 u = __builtin_bit_cast(u32, f);
    return (u + 0x7FFFu + ((u >> 16) & 1u)) >> 16;   // round-to-nearest-even
}
__device__ __forceinline__ float bf2f(u32 b) {
    return __builtin_bit_cast(float, b << 16);
}
__device__ __forceinline__ void gll16(const void* g, void* l) {
    __builtin_amdgcn_global_load_lds(
        (const __attribute__((address_space(1))) u32*)g,
        (__attribute__((address_space(3))) u32*)l, 16, 0, 0);
}

// bf16(32+v) = 0x4200 | (v<<2); q*0x4004 = q<<14|q<<2 -> packed bf16x2.
#define BFCVT(q) ((u32)((__mul24((int)(q), 0x4004) & 0x003C003C) | 0x42004200))

// Kernel 1: x f32 -> bf16 (RN) + per-row sums of the ROUNDED values.
__global__ __launch_bounds__(256) void prep_kernel(const float* __restrict__ x,
                                                   ushort* __restrict__ xbf,
                                                   float* __restrict__ rowsum) {
    const int row = blockIdx.x;
    const int tid = threadIdx.x;
    const float* xr = x + (size_t)row * K_DIM;
    ushort* br = xbf + (size_t)row * K_DIM;
    float s = 0.0f;
#pragma unroll
    for (int p = 0; p < 4; ++p) {
        int i = p * 1024 + tid * 4;
        float4 v = *reinterpret_cast<const float4*>(xr + i);
        u32 b0 = f2bf_rn(v.x), b1 = f2bf_rn(v.y), b2 = f2bf_rn(v.z), b3 = f2bf_rn(v.w);
        uint2 o;
        o.x = b0 | (b1 << 16);
        o.y = b2 | (b3 << 16);
        *reinterpret_cast<uint2*>(br + i) = o;
        s += bf2f(b0) + bf2f(b1) + bf2f(b2) + bf2f(b3);
    }
#pragma unroll
    for (int off = 32; off > 0; off >>= 1) s += __shfl_down(s, off, 64);
    __shared__ float wsum[4];
    if ((tid & 63) == 0) wsum[tid >> 6] = s;
    __syncthreads();
    if (tid == 0) rowsum[row] = wsum[0] + wsum[1] + wsum[2] + wsum[3];
}

// Kernel 2: r20 config (best: 50.56 us total) with ONE barrier per tile.
// BM=128, BN=128, BK=32, split-K=4, grid 688 (8*86), 4 waves (2m x 2n),
// wave tile 64x64, 48 KB triple-buffered LDS -> 3 blocks/CU.  Depth-1
// prefetch makes single-barrier race-free: stage target (t+1)%3 is distinct
// from both compute buf t%3 and any laggard's read buf (t-1)%3.
__global__ __launch_bounds__(256, 3) void gemm_kernel(const int* __restrict__ qw,
                                                      const float* __restrict__ scales,
                                                      const float* __restrict__ zeroes,
                                                      const ushort* __restrict__ xbf,
                                                      const float* __restrict__ rowsum,
                                                      float* __restrict__ out,
                                                      ushort* __restrict__ partial,
                                                      int split4) {
    // A tile: [m 0..127][chunk 0..3 of 16B], stored chunk' = chunk ^ ((m>>1)&3)
    // B tile: [row 0..15][col 0..127] dwords, stored col' = col ^ (((row>>2)&1)<<4)
    __shared__ uint4 Alds[3][512];    // 3 x 8 KB
    __shared__ u32   Blds[3][2048];   // 3 x 8 KB

    const u32* qwu = (const u32*)qw;
    const int tid  = threadIdx.x;
    const int lane = tid & 63;
    const int wid  = tid >> 6;
    const int l4   = lane & 15;
    const int c    = lane >> 4;

    // XCD-bijective swizzle (688 = 8*86): the 8 blocks (2mb x 4sp) of one
    // n-strip are consecutive wg -> same XCD L2 for the shared B slice.
    const int orig = blockIdx.x;
    int nb, mb, sp, NTt;
    if (split4) {
        int wg = (orig & 7) * 86 + (orig >> 3);
        nb = wg >> 3; sp = (wg >> 1) & 3; mb = wg & 1; NTt = 32;
    } else {
        nb = orig >> 1; mb = orig & 1; sp = 0; NTt = 128;
    }
    const int n0 = nb * 128;
    const int m0 = mb * 128;
    const int wm = wid >> 1;
    const int wn = wid & 1;

    // ---- staging sources (pre-swizzled so linear LDS dest = swizzled layout)
    const ushort* asrc[2];
#pragma unroll
    for (int j = 0; j < 2; ++j)
        asrc[j] = xbf + (size_t)(m0 + j * 64 + wid * 16 + (lane >> 2)) * K_DIM +
                  sp * 1024 + 8 * ((lane & 3) ^ ((lane >> 3) & 3));
    const u32* bsrc[2];
#pragma unroll
    for (int r = 0; r < 2; ++r)
        bsrc[r] = qwu + (size_t)(sp * 512 + r * 8 + wid * 2 + (lane >> 5)) * N_DIM +
                  n0 + 4 * ((lane & 31) ^ (((wid >> 1) & 1) << 2));

    // ---- LDS read byte-offsets (within one buffer)
    const u32 aoff  = (u32)((wm * 64 + l4) * 64 + ((c ^ ((l4 >> 1) & 3)) << 4));
    const u32 b0off = (u32)((c * 4) * 512 + (wn * 64 + ((c & 1) << 4) + l4) * 4);
    const u32 b1off = (u32)((c * 4) * 512 + (wn * 64 + ((1 ^ (c & 1)) << 4) + l4) * 4);

    frag_cd acc[4][4];
#pragma unroll
    for (int i = 0; i < 4; ++i)
#pragma unroll
        for (int j = 0; j < 4; ++j)
            acc[i][j] = (frag_cd){0.f, 0.f, 0.f, 0.f};

    auto stage = [&](int t, int buf) {      // 4 x global_load_lds(16B)
#pragma unroll
        for (int j = 0; j < 2; ++j)
            gll16(asrc[j] + (size_t)t * 32, &Alds[buf][j * 256 + wid * 64]);
#pragma unroll
        for (int r = 0; r < 2; ++r)
            gll16(bsrc[r] + (size_t)t * 16 * N_DIM, &Blds[buf][r * 1024 + wid * 256]);
    };

    // Grouped compute (r20-verified): issue all reads, consume in 4
    // lgkm-counted groups so MFMAs overlap remaining B-read latency.
    auto compute = [&](int buf) {
        lds_cc* Ab = (lds_cc*)&Alds[buf][0];
        lds_cc* Bb = (lds_cc*)&Blds[buf][0];
        frag_ab afr[4];
        DSR128(afr[0], Ab + aoff, 0);
        DSR128(afr[1], Ab + aoff, 1024);
        DSR128(afr[2], Ab + aoff, 2048);
        DSR128(afr[3], Ab + aoff, 3072);
        u32 bq[16];   // nf-major issue: nf = group, p = 0..3
        DSR32(bq[0],  Bb + b0off, 0);      // nf0
        DSR32(bq[1],  Bb + b0off, 512);
        DSR32(bq[2],  Bb + b0off, 1024);
        DSR32(bq[3],  Bb + b0off, 1536);
        DSR32(bq[4],  Bb + b1off, 0);      // nf1
        DSR32(bq[5],  Bb + b1off, 512);
        DSR32(bq[6],  Bb + b1off, 1024);
        DSR32(bq[7],  Bb + b1off, 1536);
        DSR32(bq[8],  Bb + b0off, 128);    // nf2
        DSR32(bq[9],  Bb + b0off, 640);
        DSR32(bq[10], Bb + b0off, 1152);
        DSR32(bq[11], Bb + b0off, 1664);
        DSR32(bq[12], Bb + b1off, 128);    // nf3
        DSR32(bq[13], Bb + b1off, 640);
        DSR32(bq[14], Bb + b1off, 1152);
        DSR32(bq[15], Bb + b1off, 1664);
        LGKM(12);
#pragma unroll
        for (int nf = 0; nf < 4; ++nf) {
            union { frag_ab f; u32 u[4]; } bb;
            bb.u[0] = BFCVT(bq[nf * 4 + 0]);
            bb.u[1] = BFCVT(bq[nf * 4 + 1]);
            bb.u[2] = BFCVT(bq[nf * 4 + 2]);
            bb.u[3] = BFCVT(bq[nf * 4 + 3]);
#pragma unroll
            for (int mf = 0; mf < 4; ++mf)
                acc[mf][nf] = __builtin_amdgcn_mfma_f32_16x16x32_bf16(
                    afr[mf], bb.f, acc[mf][nf], 0, 0, 0);
            if (nf == 0)      LGKM(8);
            else if (nf == 1) LGKM(4);
            else if (nf == 2) LGKM(0);
        }
    };

    // prologue: depth-1 prefetch
    stage(0, 0);

    int cur = 0;
    for (int t = 0; t < NTt; ++t) {
        int pbuf = cur + 1; if (pbuf >= 3) pbuf -= 3;
        if (t + 1 < NTt) {
            stage(t + 1, pbuf);
            VMW(4);                       // tile t's 4 loads landed; t+1 in flight
        } else {
            VMW(0);
        }
        __builtin_amdgcn_s_barrier();     // single barrier per tile
        __builtin_amdgcn_sched_barrier(0);
        compute(cur);
        ++cur; if (cur >= 3) cur -= 3;
    }

    // epilogue: cols n0 + wn*64 + nf*16 + l4, rows m0 + wm*64 + mf*16 + c*4 + j
    float sc[4], zp[4];
#pragma unroll
    for (int nf = 0; nf < 4; ++nf) {
        int n = n0 + wn * 64 + nf * 16 + l4;
        sc[nf] = scales[n];
        zp[nf] = zeroes[n] + 32.0f * sc[nf];
    }
    if (sp == 0) {
        float rs[4][4];
#pragma unroll
        for (int mf = 0; mf < 4; ++mf)
#pragma unroll
            for (int j = 0; j < 4; ++j)
                rs[mf][j] = rowsum[m0 + wm * 64 + mf * 16 + c * 4 + j];
#pragma unroll
        for (int mf = 0; mf < 4; ++mf)
#pragma unroll
            for (int nf = 0; nf < 4; ++nf)
#pragma unroll
                for (int j = 0; j < 4; ++j) {
                    int m = m0 + wm * 64 + mf * 16 + c * 4 + j;
                    out[(size_t)m * N_DIM + n0 + wn * 64 + nf * 16 + l4] =
                        sc[nf] * acc[mf][nf][j] - zp[nf] * rs[mf][j];
                }
    } else {
        ushort* pb = partial + (size_t)(sp - 1) * M_DIM * N_DIM;
#pragma unroll
        for (int mf = 0; mf < 4; ++mf)
#pragma unroll
            for (int nf = 0; nf < 4; ++nf)
#pragma unroll
                for (int j = 0; j < 4; ++j) {
                    int m = m0 + wm * 64 + mf * 16 + c * 4 + j;
                    pb[(size_t)m * N_DIM + n0 + wn * 64 + nf * 16 + l4] =
                        (ushort)f2bf_rn(sc[nf] * acc[mf][nf][j]);
                }
    }
}

// Kernel 3: out += bf16-partials p0+p1+p2.  Exact cover: 2752 blocks *
// 256 threads * 4 floats = 2,818,048 = 256*11008.
__global__ __launch_bounds__(256) void reduce_kernel(float* __restrict__ out,
                                                     const ushort* __restrict__ partial) {
    const size_t NTOT = (size_t)M_DIM * N_DIM;
    size_t i = ((size_t)blockIdx.x * 256 + threadIdx.x) * 4;
    float4 o = *reinterpret_cast<float4*>(out + i);
    ushort4 a = *reinterpret_cast<const ushort4*>(partial + i);
    ushort4 b = *reinterpret_cast<const ushort4*>(partial + NTOT + i);
    ushort4 d = *reinterpret_cast<const ushort4*>(partial + 2 * NTOT + i);
    o.x += bf2f(a.x) + bf2f(b.x) + bf2f(d.x);
    o.y += bf2f(a.y) + bf2f(b.y) + bf2f(d.y);
    o.z += bf2f(a.z) + bf2f(b.z) + bf2f(d.z);
    o.w += bf2f(a.w) + bf2f(b.w) + bf2f(d.w);
    *reinterpret_cast<float4*>(out + i) = o;
}

extern "C" void kernel_launch(void* const* d_in, const int* in_sizes, int n_in,
                              void* d_out, int out_size, void* d_ws, size_t ws_size,
                              hipStream_t stream) {
    const float* x      = (const float*)d_in[0];
    const int*   qw     = (const int*)d_in[1];
    const float* scales = (const float*)d_in[2];
    const float* zeroes = (const float*)d_in[3];
    float* out = (float*)d_out;

    const size_t XBF_BYTES = (size_t)M_DIM * K_DIM * 2;        // 2 MB
    const size_t RS_OFF    = XBF_BYTES;                         // 1 KB
    const size_t P_OFF     = XBF_BYTES + 4096;
    const size_t P_BYTES   = (size_t)3 * M_DIM * N_DIM * 2;     // 16.9 MB bf16

    ushort* xbf    = (ushort*)d_ws;
    float*  rowsum = (float*)((char*)d_ws + RS_OFF);
    ushort* part   = (ushort*)((char*)d_ws + P_OFF);

    const bool split4 = ws_size >= P_OFF + P_BYTES;

    prep_kernel<<<M_DIM, 256, 0, stream>>>(x, xbf, rowsum);
    if (split4) {
        gemm_kernel<<<688, 256, 0, stream>>>(qw, scales, zeroes, xbf, rowsum,
                                             out, part, 1);
        reduce_kernel<<<(M_DIM * N_DIM) / (256 * 4), 256, 0, stream>>>(out, part);
    } else {
        gemm_kernel<<<172, 256, 0, stream>>>(qw, scales, zeroes, xbf, rowsum,
                                             out, nullptr, 0);
    }
}

// Round 23
// 48.379 us; speedup vs baseline: 1.0903x; 1.0158x over previous
//
#include <hip/hip_runtime.h>
#include <stdint.h>

#define K_DIM 4096
#define N_DIM 11008
#define M_DIM 256

typedef uint32_t u32;
using frag_ab = __attribute__((ext_vector_type(8))) short;   // 8 bf16
using frag_cd = __attribute__((ext_vector_type(4))) float;   // 4 f32
using u32x4   = __attribute__((ext_vector_type(4))) uint32_t;

typedef __attribute__((address_space(3))) const char lds_cc;

#define DSR128(dst, addr, off)                                       \
    asm volatile("ds_read_b128 %0, %1 offset:" #off                  \
                 : "=&v"(dst) : "v"(addr))
#define LGKM(n) do { asm volatile("s_waitcnt lgkmcnt(" #n ")" ::: "memory"); \
                     __builtin_amdgcn_sched_barrier(0); } while (0)
#define VMW(n) asm volatile("s_waitcnt vmcnt(" #n ")" ::: "memory")

__device__ __forceinline__ u32 f2bf_rn(float f) {
    u32 u = __builtin_bit_cast(u32, f);
    return (u + 0x7FFFu + ((u >> 16) & 1u)) >> 16;   // round-to-nearest-even
}
__device__ __forceinline__ float bf2f(u32 b) {
    return __builtin_bit_cast(float, b << 16);
}
__device__ __forceinline__ void gll16(const void* g, void* l) {
    __builtin_amdgcn_global_load_lds(
        (const __attribute__((address_space(1))) u32*)g,
        (__attribute__((address_space(3))) u32*)l, 16, 0, 0);
}

// bf16(32+v) = 0x4200 | (v<<2); q*0x4004 = q<<14|q<<2 -> packed bf16x2.
#define BFCVT(q) ((u32)((__mul24((int)(q), 0x4004) & 0x003C003C) | 0x42004200))

// Kernel 1: x f32 -> bf16 (RN) + per-row sums of the ROUNDED values.
__global__ __launch_bounds__(256) void prep_kernel(const float* __restrict__ x,
                                                   ushort* __restrict__ xbf,
                                                   float* __restrict__ rowsum) {
    const int row = blockIdx.x;
    const int tid = threadIdx.x;
    const float* xr = x + (size_t)row * K_DIM;
    ushort* br = xbf + (size_t)row * K_DIM;
    float s = 0.0f;
#pragma unroll
    for (int p = 0; p < 4; ++p) {
        int i = p * 1024 + tid * 4;
        float4 v = *reinterpret_cast<const float4*>(xr + i);
        u32 b0 = f2bf_rn(v.x), b1 = f2bf_rn(v.y), b2 = f2bf_rn(v.z), b3 = f2bf_rn(v.w);
        uint2 o;
        o.x = b0 | (b1 << 16);
        o.y = b2 | (b3 << 16);
        *reinterpret_cast<uint2*>(br + i) = o;
        s += bf2f(b0) + bf2f(b1) + bf2f(b2) + bf2f(b3);
    }
#pragma unroll
    for (int off = 32; off > 0; off >>= 1) s += __shfl_down(s, off, 64);
    __shared__ float wsum[4];
    if ((tid & 63) == 0) wsum[tid >> 6] = s;
    __syncthreads();
    if (tid == 0) rowsum[row] = wsum[0] + wsum[1] + wsum[2] + wsum[3];
}

// Kernel 2: r22 structure (single barrier, depth-1, split-K=4, grid 688) +
// col-group B fragments: fragment j = cols==j mod 4, so each lane's per-p
// B needs are one contiguous 16B chunk -> B read as 4x ds_read_b128
// (was 16x ds_read_b32).  LDS chunk ci = row*32 + wn*16 + l4.
__global__ __launch_bounds__(256, 3) void gemm_kernel(const int* __restrict__ qw,
                                                      const float* __restrict__ scales,
                                                      const float* __restrict__ zeroes,
                                                      const ushort* __restrict__ xbf,
                                                      const float* __restrict__ rowsum,
                                                      float* __restrict__ out,
                                                      ushort* __restrict__ partial,
                                                      int split4) {
    // A tile: [m 0..127][chunk 0..3 of 16B], stored chunk' = chunk ^ ((m>>1)&3)
    // B tile: chunk ci = row*32 + wn*16 + l4 holds B[row][wn*64+4*l4 .. +3]
    __shared__ uint4 Alds[3][512];    // 3 x 8 KB
    __shared__ u32   Blds[3][2048];   // 3 x 8 KB

    const u32* qwu = (const u32*)qw;
    const int tid  = threadIdx.x;
    const int lane = tid & 63;
    const int wid  = tid >> 6;
    const int l4   = lane & 15;
    const int c    = lane >> 4;

    // XCD-bijective swizzle (688 = 8*86): the 8 blocks (2mb x 4sp) of one
    // n-strip are consecutive wg -> same XCD L2 for the shared B slice.
    const int orig = blockIdx.x;
    int nb, mb, sp, NTt;
    if (split4) {
        int wg = (orig & 7) * 86 + (orig >> 3);
        nb = wg >> 3; sp = (wg >> 1) & 3; mb = wg & 1; NTt = 32;
    } else {
        nb = orig >> 1; mb = orig & 1; sp = 0; NTt = 128;
    }
    const int n0 = nb * 128;
    const int m0 = mb * 128;
    const int wm = wid >> 1;
    const int wn = wid & 1;

    // ---- A staging (r22-verified pre-swizzle)
    const ushort* asrc[2];
#pragma unroll
    for (int j = 0; j < 2; ++j)
        asrc[j] = xbf + (size_t)(m0 + j * 64 + wid * 16 + (lane >> 2)) * K_DIM +
                  sp * 1024 + 8 * ((lane & 3) ^ ((lane >> 3) & 3));
    // ---- B staging: round r stages chunk ci = r*256 + wid*64 + lane;
    //      row = ci>>5 = r*8 + wid*2 + (lane>>5); wn = (lane>>4)&1; l4g = lane&15.
    //      Global: 16B-contiguous cols (4*l4g .. +3) -> gll16-legal.
    const u32* bsrc[2];
#pragma unroll
    for (int r = 0; r < 2; ++r)
        bsrc[r] = qwu + (size_t)(sp * 512 + r * 8 + wid * 2 + (lane >> 5)) * N_DIM +
                  n0 + ((lane >> 4) & 1) * 64 + 4 * (lane & 15);

    // ---- LDS read byte-offsets
    const u32 aoff = (u32)((wm * 64 + l4) * 64 + ((c ^ ((l4 >> 1) & 3)) << 4));
    const u32 boff = (u32)(c * 2048 + wn * 256 + l4 * 16);   // p stride = 512B

    frag_cd acc[4][4];   // [mf][col-group j]
#pragma unroll
    for (int i = 0; i < 4; ++i)
#pragma unroll
        for (int j = 0; j < 4; ++j)
            acc[i][j] = (frag_cd){0.f, 0.f, 0.f, 0.f};

    auto stage = [&](int t, int buf) {      // 4 x global_load_lds(16B)
#pragma unroll
        for (int j = 0; j < 2; ++j)
            gll16(asrc[j] + (size_t)t * 32, &Alds[buf][j * 256 + wid * 64]);
#pragma unroll
        for (int r = 0; r < 2; ++r)
            gll16(bsrc[r] + (size_t)t * 16 * N_DIM,
                  &Blds[buf][(r * 256 + wid * 64) * 4]);
    };

    // compute: B x4 b128 + A x4 b128; stepped lgkm so BFCVT overlaps A-reads
    // and each mf MFMA group admits one more A.
    auto compute = [&](int buf) {
        lds_cc* Ab = (lds_cc*)&Alds[buf][0];
        lds_cc* Bb = (lds_cc*)&Blds[buf][0];
        u32x4 bqp[4];
        DSR128(bqp[0], Bb + boff, 0);
        DSR128(bqp[1], Bb + boff, 512);
        DSR128(bqp[2], Bb + boff, 1024);
        DSR128(bqp[3], Bb + boff, 1536);
        frag_ab afr[4];
        DSR128(afr[0], Ab + aoff, 0);
        DSR128(afr[1], Ab + aoff, 1024);
        DSR128(afr[2], Ab + aoff, 2048);
        DSR128(afr[3], Ab + aoff, 3072);
        LGKM(4);   // B0..3 landed (in-order DS completion)
        union { frag_ab f; u32 u[4]; } bb[4];
#pragma unroll
        for (int j = 0; j < 4; ++j) {
            bb[j].u[0] = BFCVT(bqp[0][j]);
            bb[j].u[1] = BFCVT(bqp[1][j]);
            bb[j].u[2] = BFCVT(bqp[2][j]);
            bb[j].u[3] = BFCVT(bqp[3][j]);
        }
        LGKM(3);
#pragma unroll
        for (int j = 0; j < 4; ++j)
            acc[0][j] = __builtin_amdgcn_mfma_f32_16x16x32_bf16(
                afr[0], bb[j].f, acc[0][j], 0, 0, 0);
        LGKM(2);
#pragma unroll
        for (int j = 0; j < 4; ++j)
            acc[1][j] = __builtin_amdgcn_mfma_f32_16x16x32_bf16(
                afr[1], bb[j].f, acc[1][j], 0, 0, 0);
        LGKM(1);
#pragma unroll
        for (int j = 0; j < 4; ++j)
            acc[2][j] = __builtin_amdgcn_mfma_f32_16x16x32_bf16(
                afr[2], bb[j].f, acc[2][j], 0, 0, 0);
        LGKM(0);
#pragma unroll
        for (int j = 0; j < 4; ++j)
            acc[3][j] = __builtin_amdgcn_mfma_f32_16x16x32_bf16(
                afr[3], bb[j].f, acc[3][j], 0, 0, 0);
    };

    // prologue: depth-1 prefetch
    stage(0, 0);

    int cur = 0;
    for (int t = 0; t < NTt; ++t) {
        int pbuf = cur + 1; if (pbuf >= 3) pbuf -= 3;
        if (t + 1 < NTt) {
            stage(t + 1, pbuf);
            VMW(4);                       // tile t's 4 loads landed; t+1 in flight
        } else {
            VMW(0);
        }
        __builtin_amdgcn_s_barrier();     // single barrier per tile (3-buf, depth-1)
        __builtin_amdgcn_sched_barrier(0);
        compute(cur);
        ++cur; if (cur >= 3) cur -= 3;
    }

    // epilogue: lane's cols = n0 + wn*64 + 4*l4 + j  (consecutive in j)
    const int ce = n0 + wn * 64 + 4 * l4;
    const float4 scv = *reinterpret_cast<const float4*>(&scales[ce]);
    const float4 zv  = *reinterpret_cast<const float4*>(&zeroes[ce]);
    const float sc[4] = {scv.x, scv.y, scv.z, scv.w};
    const float zp[4] = {zv.x + 32.0f * scv.x, zv.y + 32.0f * scv.y,
                         zv.z + 32.0f * scv.z, zv.w + 32.0f * scv.w};
    if (sp == 0) {
#pragma unroll
        for (int mf = 0; mf < 4; ++mf) {
            const float4 rs = *reinterpret_cast<const float4*>(
                &rowsum[m0 + wm * 64 + mf * 16 + c * 4]);
            const float rsa[4] = {rs.x, rs.y, rs.z, rs.w};
#pragma unroll
            for (int jr = 0; jr < 4; ++jr) {
                int m = m0 + wm * 64 + mf * 16 + c * 4 + jr;
                float4 o;
                o.x = sc[0] * acc[mf][0][jr] - zp[0] * rsa[jr];
                o.y = sc[1] * acc[mf][1][jr] - zp[1] * rsa[jr];
                o.z = sc[2] * acc[mf][2][jr] - zp[2] * rsa[jr];
                o.w = sc[3] * acc[mf][3][jr] - zp[3] * rsa[jr];
                *reinterpret_cast<float4*>(&out[(size_t)m * N_DIM + ce]) = o;
            }
        }
    } else {
        ushort* pb = partial + (size_t)(sp - 1) * M_DIM * N_DIM;
#pragma unroll
        for (int mf = 0; mf < 4; ++mf)
#pragma unroll
            for (int jr = 0; jr < 4; ++jr) {
                int m = m0 + wm * 64 + mf * 16 + c * 4 + jr;
                ushort4 o;
                o.x = (ushort)f2bf_rn(sc[0] * acc[mf][0][jr]);
                o.y = (ushort)f2bf_rn(sc[1] * acc[mf][1][jr]);
                o.z = (ushort)f2bf_rn(sc[2] * acc[mf][2][jr]);
                o.w = (ushort)f2bf_rn(sc[3] * acc[mf][3][jr]);
                *reinterpret_cast<ushort4*>(&pb[(size_t)m * N_DIM + ce]) = o;
            }
    }
}

// Kernel 3: out += bf16-partials p0+p1+p2.  Exact cover: 2752 blocks *
// 256 threads * 4 floats = 2,818,048 = 256*11008.
__global__ __launch_bounds__(256) void reduce_kernel(float* __restrict__ out,
                                                     const ushort* __restrict__ partial) {
    const size_t NTOT = (size_t)M_DIM * N_DIM;
    size_t i = ((size_t)blockIdx.x * 256 + threadIdx.x) * 4;
    float4 o = *reinterpret_cast<float4*>(out + i);
    ushort4 a = *reinterpret_cast<const ushort4*>(partial + i);
    ushort4 b = *reinterpret_cast<const ushort4*>(partial + NTOT + i);
    ushort4 d = *reinterpret_cast<const ushort4*>(partial + 2 * NTOT + i);
    o.x += bf2f(a.x) + bf2f(b.x) + bf2f(d.x);
    o.y += bf2f(a.y) + bf2f(b.y) + bf2f(d.y);
    o.z += bf2f(a.z) + bf2f(b.z) + bf2f(d.z);
    o.w += bf2f(a.w) + bf2f(b.w) + bf2f(d.w);
    *reinterpret_cast<float4*>(out + i) = o;
}

extern "C" void kernel_launch(void* const* d_in, const int* in_sizes, int n_in,
                              void* d_out, int out_size, void* d_ws, size_t ws_size,
                              hipStream_t stream) {
    const float* x      = (const float*)d_in[0];
    const int*   qw     = (const int*)d_in[1];
    const float* scales = (const float*)d_in[2];
    const float* zeroes = (const float*)d_in[3];
    float* out = (float*)d_out;

    const size_t XBF_BYTES = (size_t)M_DIM * K_DIM * 2;        // 2 MB
    const size_t RS_OFF    = XBF_BYTES;                         // 1 KB
    const size_t P_OFF     = XBF_BYTES + 4096;
    const size_t P_BYTES   = (size_t)3 * M_DIM * N_DIM * 2;     // 16.9 MB bf16

    ushort* xbf    = (ushort*)d_ws;
    float*  rowsum = (float*)((char*)d_ws + RS_OFF);
    ushort* part   = (ushort*)((char*)d_ws + P_OFF);

    const bool split4 = ws_size >= P_OFF + P_BYTES;

    prep_kernel<<<M_DIM, 256, 0, stream>>>(x, xbf, rowsum);
    if (split4) {
        gemm_kernel<<<688, 256, 0, stream>>>(qw, scales, zeroes, xbf, rowsum,
                                             out, part, 1);
        reduce_kernel<<<(M_DIM * N_DIM) / (256 * 4), 256, 0, stream>>>(out, part);
    } else {
        gemm_kernel<<<172, 256, 0, stream>>>(qw, scales, zeroes, xbf, rowsum,
                                             out, nullptr, 0);
    }
}